// Round 1
// baseline (728.100 us; speedup 1.0000x reference)
//
#include <hip/hip_runtime.h>
#include <hip/hip_bf16.h>

#define N_NODES 50000
#define N_EDGES 800000
#define IN_FEAT 100
#define OUT_FEAT 100
#define NUM_RELS 200
#define NUM_HEADS 3

#define KP 128          // padded K (100 -> 128)
#define NPH 112         // per-head padded N (100 -> 112 = 7*16)
#define NP  336         // 3 * 112
#define MB  128         // edges per block
#define NT_ALL 21       // NP/16
#define NT_O 7          // NPH/16

typedef __attribute__((ext_vector_type(8))) short short8;
typedef __attribute__((ext_vector_type(4))) float f32x4;

__device__ __forceinline__ unsigned short f2bf(float f) {
    unsigned u = __builtin_bit_cast(unsigned, f);
    unsigned r = u + 0x7FFFu + ((u >> 16) & 1u);
    return (unsigned short)(r >> 16);
}

// ---------------------------------------------------------------------------
// Prep: build B = fc_w^T (bf16), layout [n=336][k-storage=128], XOR-swizzled,
// written to d_ws so edge blocks can copy it linearly into LDS.
// k-storage order within granule g (=kt*4+g4), elem j2 in [0,8):
//   k = kt*32 + (j2>>2)*16 + g4*4 + (j2&3)
// ---------------------------------------------------------------------------
__global__ __launch_bounds__(256) void build_B(const float* __restrict__ fc_w,
                                               unsigned short* __restrict__ Bws) {
    int idx = blockIdx.x * 256 + threadIdx.x;     // granule id: n*16 + g
    if (idx >= NP * 16) return;
    int n = idx >> 4, g = idx & 15;
    int head = n / NPH, o = n - head * NPH;
    int kt = g >> 2, g4 = g & 3;
    unsigned p[4];
#pragma unroll
    for (int half = 0; half < 2; ++half) {
#pragma unroll
        for (int jp = 0; jp < 2; ++jp) {
            int k_lo = kt * 32 + half * 16 + g4 * 4 + jp * 2;
            int k_hi = k_lo + 1;
            float vlo = (k_lo < IN_FEAT && o < OUT_FEAT)
                      ? fc_w[k_lo * (OUT_FEAT * NUM_HEADS) + head * OUT_FEAT + o] : 0.f;
            float vhi = (k_hi < IN_FEAT && o < OUT_FEAT)
                      ? fc_w[k_hi * (OUT_FEAT * NUM_HEADS) + head * OUT_FEAT + o] : 0.f;
            p[half * 2 + jp] = (unsigned)f2bf(vlo) | ((unsigned)f2bf(vhi) << 16);
        }
    }
    unsigned off = ((unsigned)(n * (KP * 2) + g * 16)) ^ (((unsigned)(n & 7)) << 4);
    *reinterpret_cast<int4*>(reinterpret_cast<char*>(Bws) + off) =
        make_int4((int)p[0], (int)p[1], (int)p[2], (int)p[3]);
}

// ---------------------------------------------------------------------------
// Self-loop init: out = h @ loop_w   (50000 x 100 x 100)
// ---------------------------------------------------------------------------
__global__ __launch_bounds__(256) void loop_kernel(const float* __restrict__ h,
                                                   const float* __restrict__ loop_w,
                                                   float* __restrict__ out) {
    __shared__ float ws[IN_FEAT * OUT_FEAT];   // 40 KB
    __shared__ float hs[2][IN_FEAT];
    for (int i = threadIdx.x; i < IN_FEAT * OUT_FEAT; i += 256) ws[i] = loop_w[i];
    int row0 = blockIdx.x * 16;
    int o  = threadIdx.x & 127;
    int rr = threadIdx.x >> 7;
    __syncthreads();
    for (int r = 0; r < 16; r += 2) {
        if (threadIdx.x < 2 * IN_FEAT) {
            int which = threadIdx.x / IN_FEAT, k = threadIdx.x - which * IN_FEAT;
            hs[which][k] = h[(row0 + r + which) * IN_FEAT + k];
        }
        __syncthreads();
        if (o < OUT_FEAT) {
            float acc = 0.f;
#pragma unroll 4
            for (int k = 0; k < IN_FEAT; ++k)
                acc = fmaf(hs[rr][k], ws[k * OUT_FEAT + o], acc);
            out[(row0 + r + rr) * OUT_FEAT + o] = acc;
        }
        __syncthreads();
    }
}

// ---------------------------------------------------------------------------
// Fused edge kernel: fc GEMM (bf16 MFMA) + attention fuse + msg + scatter-add
// Block: 512 threads (8 waves), 128 edges. Each wave owns 16 edges x 336 cols.
// ---------------------------------------------------------------------------
__global__ __launch_bounds__(512, 2) void edge_kernel(
        const float* __restrict__ h, const float* __restrict__ efeat,
        const float* __restrict__ norm, const float* __restrict__ weight,
        const float* __restrict__ attn, const int* __restrict__ rel,
        const int* __restrict__ src, const int* __restrict__ dst,
        const unsigned short* __restrict__ Bws, float* __restrict__ out) {

    __shared__ unsigned short Alds[MB * KP];   // 32768 B, swizzled
    __shared__ unsigned short Blds[NP * KP];   // 86016 B, swizzled (copied as-is)
    __shared__ int   m_rel[MB];
    __shared__ int   m_src[MB];
    __shared__ int   m_dst[MB];
    __shared__ float m_nrm[MB];

    const int tid = threadIdx.x;
    const int ebase = blockIdx.x * MB;

    // ---- stage B: linear int4 copy (layout already final, incl. swizzle) ----
    {
        const int4* sp = reinterpret_cast<const int4*>(Bws);
        int4* dp = reinterpret_cast<int4*>(Blds);
        for (int i = tid; i < NP * KP / 8; i += 512) dp[i] = sp[i];
    }
    // ---- stage edge metadata ----
    if (tid < MB) {
        int ei = ebase + tid;
        int rl = rel[ei]; int sr = src[ei]; int d = dst[ei];
        m_rel[tid] = rl; m_src[tid] = sr; m_dst[tid] = d; m_nrm[tid] = norm[d];
    }
    // ---- stage A: e rows f32 -> bf16, swizzled; 2048 granules, 4/thread ----
    for (int gi = tid; gi < MB * 16; gi += 512) {
        int row = gi >> 4, g = gi & 15;
        int kt = g >> 2, g4 = g & 3;
        const float* erow = efeat + (size_t)(ebase + row) * IN_FEAT;
        int k0 = kt * 32 + g4 * 4;
        int k1 = k0 + 16;
        float4 va = (k0 + 4 <= IN_FEAT) ? *reinterpret_cast<const float4*>(erow + k0)
                                        : make_float4(0.f, 0.f, 0.f, 0.f);
        float4 vb = (k1 + 4 <= IN_FEAT) ? *reinterpret_cast<const float4*>(erow + k1)
                                        : make_float4(0.f, 0.f, 0.f, 0.f);
        unsigned p0 = (unsigned)f2bf(va.x) | ((unsigned)f2bf(va.y) << 16);
        unsigned p1 = (unsigned)f2bf(va.z) | ((unsigned)f2bf(va.w) << 16);
        unsigned p2 = (unsigned)f2bf(vb.x) | ((unsigned)f2bf(vb.y) << 16);
        unsigned p3 = (unsigned)f2bf(vb.z) | ((unsigned)f2bf(vb.w) << 16);
        unsigned off = ((unsigned)(row * (KP * 2) + g * 16)) ^ (((unsigned)(row & 7)) << 4);
        *reinterpret_cast<int4*>(reinterpret_cast<char*>(Alds) + off) =
            make_int4((int)p0, (int)p1, (int)p2, (int)p3);
    }
    __syncthreads();

    // ---- MFMA main loop ----
    const int wave = tid >> 6;
    const int lane = tid & 63;
    const int lrow = lane & 15;   // m (A) / n (B) within tile
    const int lk   = lane >> 4;   // k-group

    f32x4 acc[NT_ALL];
#pragma unroll
    for (int i = 0; i < NT_ALL; ++i) acc[i] = (f32x4){0.f, 0.f, 0.f, 0.f};

    const int arow = wave * 16 + lrow;
    const unsigned aswz = ((unsigned)(arow & 7)) << 4;
    const unsigned nswz = ((unsigned)(lrow & 7)) << 4;   // n&7 == lrow&7 (tiles are 16-aligned)

#pragma unroll
    for (int kt = 0; kt < 4; ++kt) {
        unsigned aoff = ((unsigned)(arow * (KP * 2) + kt * 64 + lk * 16)) ^ aswz;
        short8 afrag = *reinterpret_cast<const short8*>(
            reinterpret_cast<const char*>(Alds) + aoff);
#pragma unroll
        for (int nt = 0; nt < NT_ALL; ++nt) {
            int n = nt * 16 + lrow;
            unsigned boff = ((unsigned)(n * (KP * 2) + kt * 64 + lk * 16)) ^ nswz;
            short8 bfrag = *reinterpret_cast<const short8*>(
                reinterpret_cast<const char*>(Blds) + boff);
            acc[nt] = __builtin_amdgcn_mfma_f32_16x16x32_bf16(afrag, bfrag, acc[nt], 0, 0, 0);
        }
    }

    // ---- epilogue: msg + attention fuse + norm scale + atomic scatter ----
    // C/D layout: col = lane&15, row(edge) = (lane>>4)*4 + reg
#pragma unroll
    for (int nt = 0; nt < NT_O; ++nt) {
        int o = nt * 16 + lrow;
        if (o < OUT_FEAT) {
#pragma unroll
            for (int r = 0; r < 4; ++r) {
                int el = wave * 16 + lk * 4 + r;
                int rl = m_rel[el];
                int sr = m_src[el];
                int d  = m_dst[el];
                float nm = m_nrm[el];
                float msg = h[sr * OUT_FEAT + o] * weight[rl * OUT_FEAT + o];
                float feat = 0.f;
#pragma unroll
                for (int hh = 0; hh < NUM_HEADS; ++hh) {
                    float v = acc[nt + NT_O * hh][r] *
                              attn[rl * (NUM_HEADS * OUT_FEAT) + hh * OUT_FEAT + o];
                    feat += (v > 0.f) ? v : 0.2f * v;
                }
                atomicAdd(&out[d * OUT_FEAT + o], (msg + feat) * nm);
            }
        }
    }
}

extern "C" void kernel_launch(void* const* d_in, const int* in_sizes, int n_in,
                              void* d_out, int out_size, void* d_ws, size_t ws_size,
                              hipStream_t stream) {
    const float* h      = (const float*)d_in[0];
    const float* efeat  = (const float*)d_in[1];
    const float* norm   = (const float*)d_in[2];
    const float* weight = (const float*)d_in[3];
    const float* attn   = (const float*)d_in[4];
    const float* fc_w   = (const float*)d_in[5];
    const float* loop_w = (const float*)d_in[6];
    const int*   rel    = (const int*)d_in[7];
    const int*   src    = (const int*)d_in[8];
    const int*   dst    = (const int*)d_in[9];
    float* out = (float*)d_out;
    unsigned short* Bws = (unsigned short*)d_ws;   // needs NP*KP*2 = 86016 B

    // 1) build bf16-transposed, pre-swizzled fc_w image in workspace
    build_B<<<(NP * 16 + 255) / 256, 256, 0, stream>>>(fc_w, Bws);
    // 2) out = h @ loop_w (initializes every element; atomics accumulate on top)
    loop_kernel<<<N_NODES / 16, 256, 0, stream>>>(h, loop_w, out);
    // 3) fused edge kernel
    edge_kernel<<<N_EDGES / MB, 512, 0, stream>>>(h, efeat, norm, weight, attn,
                                                  rel, src, dst, Bws, out);
}